// Round 4
// baseline (1808.232 us; speedup 1.0000x reference)
//
#include <hip/hip_runtime.h>
#include <hip/hip_bf16.h>
#include <cstddef>

// ---------------------------------------------------------------------------
// EncoderModule: 5x causal conv1d (K=7) + ELU, then 2x VQ argmin (1024 codes, D=64)
// B=64, L=48000, strides 2,2,2,3,1; channels 1->16->32->64->64->128
// Output: int32 indices, shape (2, 64, 2000)
// ---------------------------------------------------------------------------

// Conv: block = 4 waves. lane = t (TT positions per lane, 64 apart), wave owns
// CO_T consecutive output channels (wave-uniform -> weight reads are s_loads).
// Input tile staged in LDS. TT=2 doubles FMAs per weight fetch.
template<int CIN, int S, int CO_T, int TT>
__global__ __launch_bounds__(256) void conv_wave_kernel(
    const float* __restrict__ x, const float* __restrict__ w,
    const float* __restrict__ bias, float* __restrict__ y,
    int B, int Lin, int Lout, int Cout)
{
    constexpr int NT   = 64 * TT;              // t-span per block
    constexpr int XLEN = (NT - 1) * S + 7;     // input span
    __shared__ float xs[CIN][XLEN];

    int tb  = blockIdx.x;
    int cbk = blockIdx.y;
    int b   = blockIdx.z;
    int t0  = tb * NT;
    int tid  = threadIdx.x;
    int lane = tid & 63;
    int wv   = __builtin_amdgcn_readfirstlane(tid >> 6);

    const float* xb = x + (size_t)b * CIN * Lin;
    int g0 = t0 * S - 6;
    for (int i = tid; i < CIN * XLEN; i += 256) {
        int ci = i / XLEN, xo = i % XLEN;
        int gx = g0 + xo;
        xs[ci][xo] = (gx >= 0 && gx < Lin) ? xb[(size_t)ci * Lin + gx] : 0.0f;
    }
    __syncthreads();

    int co0 = cbk * (4 * CO_T) + wv * CO_T;    // uniform per wave
    const float* wbase = w + (size_t)co0 * CIN * 7;

    float acc[CO_T][TT];
    #pragma unroll
    for (int c = 0; c < CO_T; ++c)
        #pragma unroll
        for (int u = 0; u < TT; ++u) acc[c][u] = 0.0f;

    for (int ci = 0; ci < CIN; ++ci) {
        float xw[TT][7];
        #pragma unroll
        for (int u = 0; u < TT; ++u)
            #pragma unroll
            for (int k = 0; k < 7; ++k)
                xw[u][k] = xs[ci][(lane + 64 * u) * S + k];
        #pragma unroll
        for (int c = 0; c < CO_T; ++c) {
            const float* wp = wbase + (size_t)c * CIN * 7 + ci * 7;  // s_load
            #pragma unroll
            for (int k = 0; k < 7; ++k) {
                float wk = wp[k];
                #pragma unroll
                for (int u = 0; u < TT; ++u)
                    acc[c][u] = fmaf(wk, xw[u][k], acc[c][u]);
            }
        }
    }

    #pragma unroll
    for (int u = 0; u < TT; ++u) {
        int t = t0 + lane + 64 * u;
        if (t < Lout) {
            #pragma unroll
            for (int c = 0; c < CO_T; ++c) {
                float v = acc[c][u] + bias[co0 + c];
                y[((size_t)b * Cout + co0 + c) * Lout + t] = v > 0.0f ? v : expm1f(v);
            }
        }
    }
}

// ---------------------------------------------------------------------------
// ||c||^2 per code
// ---------------------------------------------------------------------------
__global__ __launch_bounds__(256) void cc_kernel(
    const float* __restrict__ cbs, float* __restrict__ cc)
{
    int c = blockIdx.x * 256 + threadIdx.x;    // 2048 codes total
    if (c >= 2048) return;
    const float4* p = (const float4*)(cbs + (size_t)c * 64);
    float s = 0.0f;
    #pragma unroll
    for (int i = 0; i < 16; ++i) {
        float4 v = p[i];
        s += v.x * v.x + v.y * v.y + v.z * v.z + v.w * v.w;
    }
    cc[c] = s;
}

// ---------------------------------------------------------------------------
// VQ: score = ||c||^2 - 2*dot(z,c). Codebook staged in LDS in 128-code chunks;
// inner reads are uniform-address ds_read_b128 broadcasts (no K$, no conflicts).
// z-row in VGPRs. Codes scanned in ascending order; strict < keeps first
// occurrence on ties (matches jnp.argmin).
// ---------------------------------------------------------------------------
#define VQ_CHUNK 128

__global__ __launch_bounds__(256) void vq_kernel(
    const float* __restrict__ z, const float* __restrict__ cbs,
    const float* __restrict__ ccg, int* __restrict__ out, int B, int T)
{
    __shared__ float cbl[VQ_CHUNK * 64];   // 32 KB
    __shared__ float ccl[VQ_CHUNK];

    int tb = blockIdx.x, cb = blockIdx.y, b = blockIdx.z;
    int tid = threadIdx.x;
    int t  = tb * 256 + tid;
    int tc = t < T ? t : T - 1;            // clamp for load, mask at store

    const float* zb = z + ((size_t)b * 128 + (size_t)cb * 64) * T;
    float zr[64];
    #pragma unroll
    for (int d = 0; d < 64; ++d) zr[d] = zb[(size_t)d * T + tc];
    #pragma unroll
    for (int d = 0; d < 64; ++d) asm volatile("" : "+v"(zr[d]));

    const float* cbase = cbs + (size_t)cb * 1024 * 64;
    const float* ccb   = ccg + cb * 1024;

    float bestv = 3.4e38f;
    int   besti = 0;

    for (int c0 = 0; c0 < 1024; c0 += VQ_CHUNK) {
        __syncthreads();   // previous chunk fully consumed
        {
            const float4* src = (const float4*)(cbase + (size_t)c0 * 64);
            float4* dst = (float4*)cbl;
            #pragma unroll
            for (int i = 0; i < (VQ_CHUNK * 16) / 256; ++i)
                dst[tid + i * 256] = src[tid + i * 256];
            if (tid < VQ_CHUNK) ccl[tid] = ccb[c0 + tid];
        }
        __syncthreads();

        #pragma unroll 2
        for (int cc_ = 0; cc_ < VQ_CHUNK; ++cc_) {
            const float4* cp4 = (const float4*)(cbl + cc_ * 64);  // uniform -> broadcast
            float d0 = 0.f, d1 = 0.f, d2 = 0.f, d3 = 0.f;
            #pragma unroll
            for (int q = 0; q < 16; ++q) {
                float4 cv = cp4[q];
                d0 = fmaf(zr[4 * q + 0], cv.x, d0);
                d1 = fmaf(zr[4 * q + 1], cv.y, d1);
                d2 = fmaf(zr[4 * q + 2], cv.z, d2);
                d3 = fmaf(zr[4 * q + 3], cv.w, d3);
            }
            float dot = (d0 + d1) + (d2 + d3);
            float s = fmaf(-2.0f, dot, ccl[cc_]);
            if (s < bestv) { bestv = s; besti = c0 + cc_; }
        }
    }
    if (t < T) out[((size_t)cb * B + b) * T + t] = besti;
}

extern "C" void kernel_launch(void* const* d_in, const int* in_sizes, int n_in,
                              void* d_out, int out_size, void* d_ws, size_t ws_size,
                              hipStream_t stream)
{
    const float* x   = (const float*)d_in[0];
    const float* w0  = (const float*)d_in[1];
    const float* b0  = (const float*)d_in[2];
    const float* w1  = (const float*)d_in[3];
    const float* b1  = (const float*)d_in[4];
    const float* w2  = (const float*)d_in[5];
    const float* b2  = (const float*)d_in[6];
    const float* w3  = (const float*)d_in[7];
    const float* b3  = (const float*)d_in[8];
    const float* wq  = (const float*)d_in[9];
    const float* bq  = (const float*)d_in[10];
    const float* cbs = (const float*)d_in[11];
    int* out = (int*)d_out;

    constexpr int B = 64;
    constexpr size_t BUF = 24576000;   // max intermediate (floats)
    float* bufA = (float*)d_ws;
    float* bufB = bufA + BUF;

    // conv0: (B,1,48000) -> (B,16,24000)   TT=2: 188 t-blocks of 128
    conv_wave_kernel<1, 2, 4, 2><<<dim3(188, 1, B), 256, 0, stream>>>(
        x, w0, b0, bufA, B, 48000, 24000, 16);
    // conv1: (B,16,24000) -> (B,32,12000)
    conv_wave_kernel<16, 2, 8, 2><<<dim3(94, 1, B), 256, 0, stream>>>(
        bufA, w1, b1, bufB, B, 24000, 12000, 32);
    // conv2: (B,32,12000) -> (B,64,6000)
    conv_wave_kernel<32, 2, 8, 2><<<dim3(47, 2, B), 256, 0, stream>>>(
        bufB, w2, b2, bufA, B, 12000, 6000, 64);
    // conv3: (B,64,6000) -> (B,64,2000)   stride 3 -> TT=1 (LDS tile)
    conv_wave_kernel<64, 3, 8, 1><<<dim3(32, 2, B), 256, 0, stream>>>(
        bufA, w3, b3, bufB, B, 6000, 2000, 64);
    // conv4: (B,64,2000) -> (B,128,2000)  stride 1
    conv_wave_kernel<64, 1, 8, 2><<<dim3(16, 4, B), 256, 0, stream>>>(
        bufB, wq, bq, bufA, B, 2000, 2000, 128);

    // ||c||^2 for both codebooks -> bufB (dead after conv4)
    float* cc = bufB;
    cc_kernel<<<8, 256, 0, stream>>>(cbs, cc);

    // VQ argmin -> out (2, B, 2000)
    vq_kernel<<<dim3(8, 2, B), 256, 0, stream>>>(bufA, cbs, cc, out, B, 2000);
}